// Round 5
// baseline (364.256 us; speedup 1.0000x reference)
//
#include <hip/hip_runtime.h>
#include <stdint.h>

typedef unsigned short u16;
typedef __attribute__((ext_vector_type(8))) short bf16x8;   // 8 bf16 (4 VGPRs)
typedef __attribute__((ext_vector_type(4))) float f32x4;
typedef __attribute__((ext_vector_type(4))) short short4v;
typedef __attribute__((ext_vector_type(8))) short short8v;
typedef __attribute__((ext_vector_type(4))) float float4v;

#define MFMA(a, b, c) __builtin_amdgcn_mfma_f32_16x16x32_bf16(a, b, c, 0, 0, 0)

__device__ __forceinline__ u16 f2bf(float f) {
  uint32_t u = __builtin_bit_cast(uint32_t, f);
  u += 0x7FFFu + ((u >> 16) & 1u);  // RNE
  return (u16)(u >> 16);
}

__device__ __forceinline__ void load_lds16(const void* g, void* lds) {
  // width-16 direct global->LDS; dest = wave-uniform base + lane*16
  __builtin_amdgcn_global_load_lds((const __attribute__((address_space(1))) void*)g,
                                   (__attribute__((address_space(3))) void*)lds, 16, 0, 0);
}

// ---------------- convert fp32 -> bf16 (x + 4 weights) ----------------
struct CvtArgs {
  const float* src[5];
  u16* dst[5];
};

__global__ __launch_bounds__(256) void convert_kernel(CvtArgs a) {
  const size_t NX = 16777216u;  // B*T*N*512
  const size_t NW = 262144u;    // 512*512
  size_t t8 = ((size_t)blockIdx.x * 256 + threadIdx.x) * 8;
  int seg;
  size_t off;
  if (t8 < NX) {
    seg = 0; off = t8;
  } else {
    size_t r = t8 - NX;
    seg = 1 + (int)(r >> 18);
    off = r & (NW - 1);
  }
  const float* s = a.src[seg] + off;
  u16* d = a.dst[seg] + off;
  float4v v0 = *((const float4v*)s);
  float4v v1 = *((const float4v*)(s + 4));
  short8v o;
  o[0] = (short)f2bf(v0[0]); o[1] = (short)f2bf(v0[1]);
  o[2] = (short)f2bf(v0[2]); o[3] = (short)f2bf(v0[3]);
  o[4] = (short)f2bf(v1[0]); o[5] = (short)f2bf(v1[1]);
  o[6] = (short)f2bf(v1[2]); o[7] = (short)f2bf(v1[3]);
  *((short8v*)d) = o;
}

// ---------------- GEMM: C[M,512] = A[M,512] * B[512,512]^T (B stored [n][k]) ----
// m97 structure: 128x128 tile, BK=64, 4 waves, global_load_lds w16, XOR-swizzled LDS.
// MODE 0: bf16 row-major out; MODE 1: fp32 row-major out; MODE 2: bf16 v_t out
//         (v_t[bt][h][c][n], bt=m/64, h=col/64, c=col%64, n=m%64)
template <int MODE>
__global__ __launch_bounds__(256) void gemm_bt(const u16* __restrict__ A,
                                               const u16* __restrict__ B,
                                               void* __restrict__ Cp) {
  __shared__ u16 lA[128 * 64];
  __shared__ u16 lB[128 * 64];
  const int tid = threadIdx.x;
  const int wave = tid >> 6, lane = tid & 63;
  const int g = lane >> 4, li = lane & 15;
  const int wr = wave >> 1, wc = wave & 1;
  const int m0 = blockIdx.x * 128, n0 = blockIdx.y * 128;
  const int rowa = tid >> 3, cl = tid & 7;

  f32x4 acc[4][4] = {};

  for (int kt = 0; kt < 8; ++kt) {
    __syncthreads();  // protect LDS from previous iteration's readers
#pragma unroll
    for (int it = 0; it < 4; ++it) {
      const int r = it * 32 + rowa;
      const int sc = (cl ^ (r & 7)) * 8;  // pre-swizzled source chunk (rule #21)
      load_lds16(A + (size_t)(m0 + r) * 512 + kt * 64 + sc,
                 lA + (it * 256 + wave * 64) * 8);
      load_lds16(B + (size_t)(n0 + r) * 512 + kt * 64 + sc,
                 lB + (it * 256 + wave * 64) * 8);
    }
    __syncthreads();  // compiler emits vmcnt(0) drain here
#pragma unroll
    for (int ks = 0; ks < 2; ++ks) {
      bf16x8 af[4], bf[4];
#pragma unroll
      for (int mi = 0; mi < 4; ++mi) {
        const int r = wr * 64 + mi * 16 + li;
        af[mi] = *(const bf16x8*)(lA + r * 64 + (((ks * 4 + g) ^ (r & 7)) * 8));
      }
#pragma unroll
      for (int ni = 0; ni < 4; ++ni) {
        const int r = wc * 64 + ni * 16 + li;
        bf[ni] = *(const bf16x8*)(lB + r * 64 + (((ks * 4 + g) ^ (r & 7)) * 8));
      }
#pragma unroll
      for (int mi = 0; mi < 4; ++mi)
#pragma unroll
        for (int ni = 0; ni < 4; ++ni)
          acc[mi][ni] = MFMA(af[mi], bf[ni], acc[mi][ni]);
    }
  }

  if constexpr (MODE == 0) {
    u16* C = (u16*)Cp;
#pragma unroll
    for (int mi = 0; mi < 4; ++mi)
#pragma unroll
      for (int ni = 0; ni < 4; ++ni) {
        const int col = n0 + wc * 64 + ni * 16 + li;
        const int row0 = m0 + wr * 64 + mi * 16 + g * 4;
#pragma unroll
        for (int r = 0; r < 4; ++r)
          C[(size_t)(row0 + r) * 512 + col] = f2bf(acc[mi][ni][r]);
      }
  } else if constexpr (MODE == 1) {
    float* C = (float*)Cp;
#pragma unroll
    for (int mi = 0; mi < 4; ++mi)
#pragma unroll
      for (int ni = 0; ni < 4; ++ni) {
        const int col = n0 + wc * 64 + ni * 16 + li;
        const int row0 = m0 + wr * 64 + mi * 16 + g * 4;
#pragma unroll
        for (int r = 0; r < 4; ++r)
          C[(size_t)(row0 + r) * 512 + col] = acc[mi][ni][r];
      }
  } else {
    u16* C = (u16*)Cp;
#pragma unroll
    for (int mi = 0; mi < 4; ++mi)
#pragma unroll
      for (int ni = 0; ni < 4; ++ni) {
        const int col = n0 + wc * 64 + ni * 16 + li;
        const int hh = col >> 6, c = col & 63;
        const int row0 = m0 + wr * 64 + mi * 16 + g * 4;
        const int bt = row0 >> 6, n = row0 & 63;
        short4v pk;
#pragma unroll
        for (int r = 0; r < 4; ++r) pk[r] = (short)f2bf(acc[mi][ni][r]);
        *(short4v*)(C + ((size_t)bt * 8 + hh) * 4096 + (size_t)c * 64 + n) = pk;
      }
  }
}

// ---------------- attention: one BLOCK per (b,t,h), lags split across 4 waves ----
// wave w handles lags {2+w, 6+w, 10+w} (<= lmax); partial accO reduced via LDS tree.
// S^T = mfma(K, Q) so softmax over j needs only 2 shfl_xor; P goes through a
// per-wave XOR-swizzled LDS tile to become the PV A-operand; V is pre-transposed.
__global__ __launch_bounds__(256) void attn_kernel(const u16* __restrict__ q,
                                                   const u16* __restrict__ k,
                                                   const u16* __restrict__ vt,
                                                   u16* __restrict__ Y) {
  __shared__ __align__(16) char lds[34816];  // 4x8KB P tiles; reused as 2x17KB reduce bufs
  const int tid = threadIdx.x;
  const int wave = tid >> 6, lane = tid & 63;
  const int g = lane >> 4, li = lane & 15;
  const int bid = blockIdx.x;  // 0..4095
  const int h = bid & 7, t = (bid >> 3) & 127, b = bid >> 10;
  u16* pw = (u16*)(lds + wave * 8192);
  float* bufA = (float*)lds;
  float* bufB = (float*)(lds + 17408);

  const size_t qoff = ((size_t)(b * 128 + t) * 64) * 512 + h * 64;
  bf16x8 qf[4][2];  // B-operand of S^T: col=i, k=c
#pragma unroll
  for (int fi = 0; fi < 4; ++fi)
#pragma unroll
    for (int ks = 0; ks < 2; ++ks)
      qf[fi][ks] = *(const bf16x8*)(q + qoff + (size_t)(fi * 16 + li) * 512 + ks * 32 + g * 8);

  f32x4 accO[4][4] = {};  // [mi(rows i)][fc(cols c)]
  const int lmax = (t < 12) ? t : 12;
  for (int j = 0; j < 3; ++j) {
    const int lag = 2 + wave + 4 * j;
    if (lag > lmax) break;  // lags increase with j
    const int s = t - lag;
    const size_t koff = ((size_t)(b * 128 + s) * 64) * 512 + h * 64;
    bf16x8 kf[4][2];  // A-operand of S^T: row=j, k=c
#pragma unroll
    for (int fj = 0; fj < 4; ++fj)
#pragma unroll
      for (int ks = 0; ks < 2; ++ks)
        kf[fj][ks] = *(const bf16x8*)(k + koff + (size_t)(fj * 16 + li) * 512 + ks * 32 + g * 8);

    f32x4 S[4][4] = {};  // S^T frags: lane holds P[i=fi*16+li][j=fj*16+g*4+r]
#pragma unroll
    for (int ks = 0; ks < 2; ++ks)
#pragma unroll
      for (int fj = 0; fj < 4; ++fj)
#pragma unroll
        for (int fi = 0; fi < 4; ++fi)
          S[fj][fi] = MFMA(kf[fj][ks], qf[fi][ks], S[fj][fi]);

    // softmax over j (scale 1/8 folded into exp2); 1/11 lag-mean folded into inv
#pragma unroll
    for (int fi = 0; fi < 4; ++fi) {
      float m = S[0][fi][0];
#pragma unroll
      for (int fj = 0; fj < 4; ++fj)
#pragma unroll
        for (int r = 0; r < 4; ++r) m = fmaxf(m, S[fj][fi][r]);
      m = fmaxf(m, __shfl_xor(m, 16));
      m = fmaxf(m, __shfl_xor(m, 32));
      float sum = 0.f;
#pragma unroll
      for (int fj = 0; fj < 4; ++fj)
#pragma unroll
        for (int r = 0; r < 4; ++r) {
          float p = exp2f((S[fj][fi][r] - m) * 0.18033688011112f);  // log2(e)/8
          S[fj][fi][r] = p;
          sum += p;
        }
      sum += __shfl_xor(sum, 16);
      sum += __shfl_xor(sum, 32);
      const float inv = 1.f / (11.f * sum);
#pragma unroll
      for (int fj = 0; fj < 4; ++fj)
#pragma unroll
        for (int r = 0; r < 4; ++r) S[fj][fi][r] *= inv;
    }

    // P -> LDS [i][j], 16B-chunk XOR swizzle on j; packed b64 writes
#pragma unroll
    for (int fj = 0; fj < 4; ++fj)
#pragma unroll
      for (int fi = 0; fi < 4; ++fi) {
        const int i = fi * 16 + li, j0 = fj * 16 + g * 4;
        short4v pk;
#pragma unroll
        for (int r = 0; r < 4; ++r) pk[r] = (short)f2bf(S[fj][fi][r]);
        const int chunk = (j0 >> 3) ^ (i & 7);
        *(short4v*)(pw + i * 64 + chunk * 8 + (j0 & 7)) = pk;
      }

    // PV: A = P (row=i, k=j), B = V^T-layout (col=c, k=j contiguous)
    const size_t voff = ((size_t)(b * 128 + s) * 8 + h) * 4096;
    bf16x8 pf[4][2], vf[4][2];
#pragma unroll
    for (int mi = 0; mi < 4; ++mi)
#pragma unroll
      for (int ks = 0; ks < 2; ++ks) {
        const int i = mi * 16 + li;
        pf[mi][ks] = *(const bf16x8*)(pw + i * 64 + (((ks * 4 + g) ^ (i & 7)) * 8));
      }
#pragma unroll
    for (int fc = 0; fc < 4; ++fc)
#pragma unroll
      for (int ks = 0; ks < 2; ++ks)
        vf[fc][ks] = *(const bf16x8*)(vt + voff + (size_t)(fc * 16 + li) * 64 + ks * 32 + g * 8);
#pragma unroll
    for (int ks = 0; ks < 2; ++ks)
#pragma unroll
      for (int mi = 0; mi < 4; ++mi)
#pragma unroll
        for (int fc = 0; fc < 4; ++fc)
          accO[mi][fc] = MFMA(pf[mi][ks], vf[fc][ks], accO[mi][fc]);
  }

  // ---- reduce partial accO across the 4 waves (pairwise tree in LDS) ----
  // per-lane row of 272B (17 x 16B) -> 16B/lane writes at structural bank floor
  __syncthreads();  // all waves done with P tiles (bufs alias them)
  {
    char* pa = (char*)bufA + lane * 272;
    char* pb = (char*)bufB + lane * 272;
    if (wave == 2) {
#pragma unroll
      for (int mi = 0; mi < 4; ++mi)
#pragma unroll
        for (int fc = 0; fc < 4; ++fc)
          *(f32x4*)(pa + (mi * 4 + fc) * 16) = accO[mi][fc];
    }
    if (wave == 3) {
#pragma unroll
      for (int mi = 0; mi < 4; ++mi)
#pragma unroll
        for (int fc = 0; fc < 4; ++fc)
          *(f32x4*)(pb + (mi * 4 + fc) * 16) = accO[mi][fc];
    }
    __syncthreads();
    if (wave == 0) {
#pragma unroll
      for (int mi = 0; mi < 4; ++mi)
#pragma unroll
        for (int fc = 0; fc < 4; ++fc)
          accO[mi][fc] += *(f32x4*)(pa + (mi * 4 + fc) * 16);
    }
    if (wave == 1) {
#pragma unroll
      for (int mi = 0; mi < 4; ++mi)
#pragma unroll
        for (int fc = 0; fc < 4; ++fc)
          accO[mi][fc] += *(f32x4*)(pb + (mi * 4 + fc) * 16);
    }
    __syncthreads();
    if (wave == 1) {
#pragma unroll
      for (int mi = 0; mi < 4; ++mi)
#pragma unroll
        for (int fc = 0; fc < 4; ++fc)
          *(f32x4*)(pa + (mi * 4 + fc) * 16) = accO[mi][fc];
    }
    __syncthreads();
    if (wave == 0) {
#pragma unroll
      for (int mi = 0; mi < 4; ++mi)
#pragma unroll
        for (int fc = 0; fc < 4; ++fc)
          accO[mi][fc] += *(f32x4*)(pa + (mi * 4 + fc) * 16);
    }
  }

  // Y[b,t,n,d] bf16, written by wave 0; t<2 writes zeros (no lag ran)
  if (wave == 0) {
#pragma unroll
    for (int mi = 0; mi < 4; ++mi)
#pragma unroll
      for (int fc = 0; fc < 4; ++fc) {
        const int d = h * 64 + fc * 16 + li;
#pragma unroll
        for (int r = 0; r < 4; ++r) {
          const int i = mi * 16 + g * 4 + r;
          Y[((size_t)(b * 128 + t) * 64 + i) * 512 + d] = f2bf(accO[mi][fc][r]);
        }
      }
  }
}

extern "C" void kernel_launch(void* const* d_in, const int* in_sizes, int n_in,
                              void* d_out, int out_size, void* d_ws, size_t ws_size,
                              hipStream_t stream) {
  (void)in_sizes; (void)n_in; (void)out_size; (void)ws_size;
  const float* x  = (const float*)d_in[0];
  const float* Wq = (const float*)d_in[1];
  const float* Wk = (const float*)d_in[2];
  const float* Wv = (const float*)d_in[3];
  const float* Wo = (const float*)d_in[4];
  // d_in[5] (lag_emb) is mathematically a no-op: constant shift along softmax axis.

  u16* ws = (u16*)d_ws;
  const size_t NX = 16777216u, NW = 262144u;
  u16* xb  = ws;            // x bf16; reused as Y after QKV GEMMs complete
  u16* wqb = xb + NX;
  u16* wkb = wqb + NW;
  u16* wvb = wkb + NW;
  u16* wob = wvb + NW;
  u16* qb  = wob + NW;
  u16* kb  = qb + NX;
  u16* vtb = kb + NX;
  u16* Yb  = xb;

  CvtArgs ca;
  ca.src[0] = x;  ca.dst[0] = xb;
  ca.src[1] = Wq; ca.dst[1] = wqb;
  ca.src[2] = Wk; ca.dst[2] = wkb;
  ca.src[3] = Wv; ca.dst[3] = wvb;
  ca.src[4] = Wo; ca.dst[4] = wob;
  convert_kernel<<<8704, 256, 0, stream>>>(ca);

  dim3 gg(256, 4);  // M/128 x 512/128
  gemm_bt<0><<<gg, 256, 0, stream>>>(xb, wqb, qb);
  gemm_bt<0><<<gg, 256, 0, stream>>>(xb, wkb, kb);
  gemm_bt<2><<<gg, 256, 0, stream>>>(xb, wvb, vtb);

  attn_kernel<<<4096, 256, 0, stream>>>(qb, kb, vtb, Yb);

  gemm_bt<1><<<gg, 256, 0, stream>>>(Yb, wob, (float*)d_out);
}

// Round 6
// 251.359 us; speedup vs baseline: 1.4491x; 1.4491x over previous
//
#include <hip/hip_runtime.h>
#include <stdint.h>

typedef unsigned short u16;
typedef __attribute__((ext_vector_type(8))) short bf16x8;   // 8 bf16 (4 VGPRs)
typedef __attribute__((ext_vector_type(4))) float f32x4;
typedef __attribute__((ext_vector_type(4))) short short4v;
typedef __attribute__((ext_vector_type(8))) short short8v;
typedef __attribute__((ext_vector_type(4))) float float4v;

#define MFMA(a, b, c) __builtin_amdgcn_mfma_f32_16x16x32_bf16(a, b, c, 0, 0, 0)

__device__ __forceinline__ u16 f2bf(float f) {
  uint32_t u = __builtin_bit_cast(uint32_t, f);
  u += 0x7FFFu + ((u >> 16) & 1u);  // RNE
  return (u16)(u >> 16);
}

__device__ __forceinline__ void load_lds16(const void* g, void* lds) {
  // width-16 direct global->LDS; dest = wave-uniform base, HW adds lane*16
  __builtin_amdgcn_global_load_lds((const __attribute__((address_space(1))) void*)g,
                                   (__attribute__((address_space(3))) void*)lds, 16, 0, 0);
}

// ---------------- convert fp32 -> bf16 (x + 4 weights) ----------------
struct CvtArgs {
  const float* src[5];
  u16* dst[5];
};

__global__ __launch_bounds__(256) void convert_kernel(CvtArgs a) {
  const size_t NX = 16777216u;  // B*T*N*512
  const size_t NW = 262144u;    // 512*512
  size_t t8 = ((size_t)blockIdx.x * 256 + threadIdx.x) * 8;
  int seg;
  size_t off;
  if (t8 < NX) {
    seg = 0; off = t8;
  } else {
    size_t r = t8 - NX;
    seg = 1 + (int)(r >> 18);
    off = r & (NW - 1);
  }
  const float* s = a.src[seg] + off;
  u16* d = a.dst[seg] + off;
  float4v v0 = *((const float4v*)s);
  float4v v1 = *((const float4v*)(s + 4));
  short8v o;
  o[0] = (short)f2bf(v0[0]); o[1] = (short)f2bf(v0[1]);
  o[2] = (short)f2bf(v0[2]); o[3] = (short)f2bf(v0[3]);
  o[4] = (short)f2bf(v1[0]); o[5] = (short)f2bf(v1[1]);
  o[6] = (short)f2bf(v1[2]); o[7] = (short)f2bf(v1[3]);
  *((short8v*)d) = o;
}

// ---------------- GEMM: C[M,512] = A[M,512] * B[512,512]^T (B stored [n][k]) ----
// m97 structure: 128x128 tile, BK=64, 4 waves, global_load_lds w16, XOR-swizzled LDS.
template <int MODE>
__global__ __launch_bounds__(256) void gemm_bt(const u16* __restrict__ A,
                                               const u16* __restrict__ B,
                                               void* __restrict__ Cp) {
  __shared__ u16 lA[128 * 64];
  __shared__ u16 lB[128 * 64];
  const int tid = threadIdx.x;
  const int wave = tid >> 6, lane = tid & 63;
  const int g = lane >> 4, li = lane & 15;
  const int wr = wave >> 1, wc = wave & 1;
  const int m0 = blockIdx.x * 128, n0 = blockIdx.y * 128;
  const int rowa = tid >> 3, cl = tid & 7;

  f32x4 acc[4][4] = {};

  for (int kt = 0; kt < 8; ++kt) {
    __syncthreads();
#pragma unroll
    for (int it = 0; it < 4; ++it) {
      const int r = it * 32 + rowa;
      const int sc = (cl ^ (r & 7)) * 8;  // pre-swizzled source chunk (rule #21)
      load_lds16(A + (size_t)(m0 + r) * 512 + kt * 64 + sc,
                 lA + (it * 256 + wave * 64) * 8);
      load_lds16(B + (size_t)(n0 + r) * 512 + kt * 64 + sc,
                 lB + (it * 256 + wave * 64) * 8);
    }
    __syncthreads();
#pragma unroll
    for (int ks = 0; ks < 2; ++ks) {
      bf16x8 af[4], bf[4];
#pragma unroll
      for (int mi = 0; mi < 4; ++mi) {
        const int r = wr * 64 + mi * 16 + li;
        af[mi] = *(const bf16x8*)(lA + r * 64 + (((ks * 4 + g) ^ (r & 7)) * 8));
      }
#pragma unroll
      for (int ni = 0; ni < 4; ++ni) {
        const int r = wc * 64 + ni * 16 + li;
        bf[ni] = *(const bf16x8*)(lB + r * 64 + (((ks * 4 + g) ^ (r & 7)) * 8));
      }
#pragma unroll
      for (int mi = 0; mi < 4; ++mi)
#pragma unroll
        for (int ni = 0; ni < 4; ++ni)
          acc[mi][ni] = MFMA(af[mi], bf[ni], acc[mi][ni]);
    }
  }

  if constexpr (MODE == 0) {
    u16* C = (u16*)Cp;
#pragma unroll
    for (int mi = 0; mi < 4; ++mi)
#pragma unroll
      for (int ni = 0; ni < 4; ++ni) {
        const int col = n0 + wc * 64 + ni * 16 + li;
        const int row0 = m0 + wr * 64 + mi * 16 + g * 4;
#pragma unroll
        for (int r = 0; r < 4; ++r)
          C[(size_t)(row0 + r) * 512 + col] = f2bf(acc[mi][ni][r]);
      }
  } else if constexpr (MODE == 1) {
    float* C = (float*)Cp;
#pragma unroll
    for (int mi = 0; mi < 4; ++mi)
#pragma unroll
      for (int ni = 0; ni < 4; ++ni) {
        const int col = n0 + wc * 64 + ni * 16 + li;
        const int row0 = m0 + wr * 64 + mi * 16 + g * 4;
#pragma unroll
        for (int r = 0; r < 4; ++r)
          C[(size_t)(row0 + r) * 512 + col] = acc[mi][ni][r];
      }
  } else {
    u16* C = (u16*)Cp;
#pragma unroll
    for (int mi = 0; mi < 4; ++mi)
#pragma unroll
      for (int ni = 0; ni < 4; ++ni) {
        const int col = n0 + wc * 64 + ni * 16 + li;
        const int hh = col >> 6, c = col & 63;
        const int row0 = m0 + wr * 64 + mi * 16 + g * 4;
        const int bt = row0 >> 6, n = row0 & 63;
        short4v pk;
#pragma unroll
        for (int r = 0; r < 4; ++r) pk[r] = (short)f2bf(acc[mi][ni][r]);
        *(short4v*)(C + ((size_t)bt * 8 + hh) * 4096 + (size_t)c * 64 + n) = pk;
      }
  }
}

// ---------------- attention: one BLOCK per (b,t,h), waves split the i-dim ----
// Wave w owns output rows i in [w*16, w*16+16). All waves share K/V tiles,
// double-buffered in LDS via global_load_lds (prefetch overlaps compute; one
// __syncthreads per lag whose built-in vmcnt drain is the staging wait).
// S^T = mfma(K, Q): lane(g,li) holds S[i=li][j=fj*16+g*4+r] -> row softmax via
// 2 shfl_xor. P goes through a per-wave 2KB swizzled LDS buf to become the PV
// A-operand; V is pre-transposed ([c][n]) by the V-GEMM epilogue.
__global__ __launch_bounds__(256) void attn_kernel(const u16* __restrict__ q,
                                                   const u16* __restrict__ k,
                                                   const u16* __restrict__ vt,
                                                   u16* __restrict__ Y) {
  __shared__ __align__(16) char lds[40960];  // 2 x (8KB K + 8KB V) dbuf + 4 x 2KB P
  const int tid = threadIdx.x;
  const int wave = tid >> 6, lane = tid & 63;
  const int g = lane >> 4, li = lane & 15;
  const int bid = blockIdx.x;  // 0..4095
  const int h = bid & 7, t = (bid >> 3) & 127, b = bid >> 10;
  char* pbuf = lds + 32768 + wave * 2048;
  const int i0 = wave * 16;
  const int sub = lane >> 3, cl = lane & 7;
  const int slot0 = wave * 4;  // this wave's 4 staging slots (of 16)

  // Q fragments (B-operand): lane(g,li) holds Q[i0+li][ks*32+g*8 + 0..7]
  const size_t qoff = ((size_t)((b * 128 + t) * 64 + i0 + li)) * 512 + h * 64;
  bf16x8 qf[2];
#pragma unroll
  for (int ks = 0; ks < 2; ++ks)
    qf[ks] = *(const bf16x8*)(q + qoff + ks * 32 + g * 8);

  f32x4 accO[4] = {};  // [fc]; lane(g,li): O[i=i0+g*4+r][c=fc*16+li]
  const int lmax = (t < 12) ? t : 12;

  // stage K/V tiles for source time s into buffer cur (4 loads per wave)
  auto stage = [&](int st, int cur) {
    char* base = lds + cur * 16384;
    const size_t koff = ((size_t)((b * 128 + st) * 64)) * 512 + h * 64;
    const size_t voff = ((size_t)((b * 128 + st) * 8 + h)) * 4096;
#pragma unroll
    for (int m = 0; m < 4; ++m) {
      const int slot = slot0 + m;
      if (slot < 8) {  // K tile rows j = slot*8 .. +7, row stride 512
        const int j = slot * 8 + sub;
        load_lds16(k + koff + (size_t)j * 512 + (cl ^ (j & 7)) * 8,
                   base + slot * 1024);
      } else {         // V^T tile rows c = (slot-8)*8 .. +7, contiguous 4096
        const int c = (slot - 8) * 8 + sub;
        load_lds16(vt + voff + c * 64 + (cl ^ (c & 7)) * 8,
                   base + 8192 + (slot - 8) * 1024);
      }
    }
  };

  if (lmax >= 2) {
    stage(t - 2, 0);
    int cur = 0;
    for (int lag = 2; lag <= lmax; ++lag) {
      __syncthreads();  // drains this wave's staging loads + syncs buffers
      if (lag < lmax) stage(t - lag - 1, cur ^ 1);  // prefetch next under compute

      const u16* kt = (const u16*)(lds + cur * 16384);
      const u16* vtile = kt + 4096;

      // S^T: 8 MFMAs (acc over ks); kf fragments straight from swizzled LDS
      f32x4 S[4] = {};
#pragma unroll
      for (int ks = 0; ks < 2; ++ks)
#pragma unroll
        for (int fj = 0; fj < 4; ++fj) {
          const int j = fj * 16 + li;
          bf16x8 kfr = *(const bf16x8*)(kt + j * 64 + (((ks * 4 + g) ^ (j & 7)) * 8));
          S[fj] = MFMA(kfr, qf[ks], S[fj]);
        }

      // row softmax over j (lane holds 16 of 64; g-groups complete the row)
      float mx = S[0][0];
#pragma unroll
      for (int fj = 0; fj < 4; ++fj)
#pragma unroll
        for (int r = 0; r < 4; ++r) mx = fmaxf(mx, S[fj][r]);
      mx = fmaxf(mx, __shfl_xor(mx, 16));
      mx = fmaxf(mx, __shfl_xor(mx, 32));
      float sum = 0.f;
#pragma unroll
      for (int fj = 0; fj < 4; ++fj)
#pragma unroll
        for (int r = 0; r < 4; ++r) {
          float p = exp2f((S[fj][r] - mx) * 0.18033688011112f);  // log2(e)/8
          S[fj][r] = p;
          sum += p;
        }
      sum += __shfl_xor(sum, 16);
      sum += __shfl_xor(sum, 32);
      const float inv = 1.f / (11.f * sum);  // 1/11 lag-mean folded in

      // P -> per-wave LDS buf [i=li][j], 16B-chunk XOR swizzle on j
#pragma unroll
      for (int fj = 0; fj < 4; ++fj) {
        const int j0 = fj * 16 + g * 4;
        short4v pk;
#pragma unroll
        for (int r = 0; r < 4; ++r) pk[r] = (short)f2bf(S[fj][r] * inv);
        const int chunk = (j0 >> 3) ^ (li & 7);
        *(short4v*)(pbuf + li * 128 + chunk * 16 + (j0 & 7) * 2) = pk;
      }

      // PV: A = P (rows i, k=j), B = V^T tile ([c][j], k=j contiguous)
      bf16x8 pf[2];
#pragma unroll
      for (int ks = 0; ks < 2; ++ks)
        pf[ks] = *(const bf16x8*)(pbuf + li * 128 + (((ks * 4 + g) ^ (li & 7)) * 16));
#pragma unroll
      for (int ks = 0; ks < 2; ++ks)
#pragma unroll
        for (int fc = 0; fc < 4; ++fc) {
          const int c = fc * 16 + li;
          bf16x8 vfr = *(const bf16x8*)(vtile + c * 64 + (((ks * 4 + g) ^ (c & 7)) * 8));
          accO[fc] = MFMA(pf[ks], vfr, accO[fc]);
        }
      cur ^= 1;
    }
  }

  // Y[b,t,n=i,d]: wave w writes its own 16 rows; t<2 writes zeros
#pragma unroll
  for (int fc = 0; fc < 4; ++fc) {
    const int d = h * 64 + fc * 16 + li;
#pragma unroll
    for (int r = 0; r < 4; ++r) {
      const int i = i0 + g * 4 + r;
      Y[((size_t)((b * 128 + t) * 64 + i)) * 512 + d] = f2bf(accO[fc][r]);
    }
  }
}

extern "C" void kernel_launch(void* const* d_in, const int* in_sizes, int n_in,
                              void* d_out, int out_size, void* d_ws, size_t ws_size,
                              hipStream_t stream) {
  (void)in_sizes; (void)n_in; (void)out_size; (void)ws_size;
  const float* x  = (const float*)d_in[0];
  const float* Wq = (const float*)d_in[1];
  const float* Wk = (const float*)d_in[2];
  const float* Wv = (const float*)d_in[3];
  const float* Wo = (const float*)d_in[4];
  // d_in[5] (lag_emb) is mathematically a no-op: constant shift along softmax axis.

  u16* ws = (u16*)d_ws;
  const size_t NX = 16777216u, NW = 262144u;
  u16* xb  = ws;            // x bf16; reused as Y after QKV GEMMs complete
  u16* wqb = xb + NX;
  u16* wkb = wqb + NW;
  u16* wvb = wkb + NW;
  u16* wob = wvb + NW;
  u16* qb  = wob + NW;
  u16* kb  = qb + NX;
  u16* vtb = kb + NX;
  u16* Yb  = xb;

  CvtArgs ca;
  ca.src[0] = x;  ca.dst[0] = xb;
  ca.src[1] = Wq; ca.dst[1] = wqb;
  ca.src[2] = Wk; ca.dst[2] = wkb;
  ca.src[3] = Wv; ca.dst[3] = wvb;
  ca.src[4] = Wo; ca.dst[4] = wob;
  convert_kernel<<<8704, 256, 0, stream>>>(ca);

  dim3 gg(256, 4);  // M/128 x 512/128
  gemm_bt<0><<<gg, 256, 0, stream>>>(xb, wqb, qb);
  gemm_bt<0><<<gg, 256, 0, stream>>>(xb, wkb, kb);
  gemm_bt<2><<<gg, 256, 0, stream>>>(xb, wvb, vtb);

  attn_kernel<<<4096, 256, 0, stream>>>(qb, kb, vtb, Yb);

  gemm_bt<1><<<gg, 256, 0, stream>>>(Yb, wob, (float*)d_out);
}